// Round 10
// baseline (590.480 us; speedup 1.0000x reference)
//
#include <hip/hip_runtime.h>
#include <hip/hip_bf16.h>
#include <math.h>

#define NV 20000
#define NE 320000
#define CSR_PAD 16
#define NREP 16                  // hist replicas per layer (LDS-local chunks)

typedef __attribute__((ext_vector_type(8))) short bf16x8;
typedef __attribute__((ext_vector_type(4))) float f32x4;
typedef __attribute__((ext_vector_type(2))) _Float16 h2;

static __device__ __forceinline__ ushort f2b(float f) {
  __hip_bfloat16 h = __float2bfloat16(f);
  return *reinterpret_cast<ushort*>(&h);
}
static __device__ __forceinline__ float b2f(ushort u) {
  union { ushort s[2]; float f; } c;
  c.s[0] = 0; c.s[1] = u;
  return c.f;
}
static __device__ __forceinline__ ushort f2h(float f) {
  _Float16 h = (_Float16)f;
  return *reinterpret_cast<ushort*>(&h);
}
static __device__ __forceinline__ float blo(unsigned u) { return __uint_as_float(u << 16); }
static __device__ __forceinline__ float bhi(unsigned u) { return __uint_as_float(u & 0xffff0000u); }
static __device__ __forceinline__ h2 u2h2(unsigned u) {
  union { unsigned v; h2 h; } c; c.v = u; return c.h;
}

// DPP wave-64 sum: lane 63 holds total, broadcast via readlane.
static __device__ __forceinline__ float wave_sum64(float x) {
  x += __int_as_float(__builtin_amdgcn_update_dpp(0, __float_as_int(x), 0x111, 0xF, 0xF, true));
  x += __int_as_float(__builtin_amdgcn_update_dpp(0, __float_as_int(x), 0x112, 0xF, 0xF, true));
  x += __int_as_float(__builtin_amdgcn_update_dpp(0, __float_as_int(x), 0x114, 0xF, 0xF, true));
  x += __int_as_float(__builtin_amdgcn_update_dpp(0, __float_as_int(x), 0x118, 0xF, 0xF, true));
  x += __int_as_float(__builtin_amdgcn_update_dpp(0, __float_as_int(x), 0x142, 0xA, 0xF, true));
  x += __int_as_float(__builtin_amdgcn_update_dpp(0, __float_as_int(x), 0x143, 0xC, 0xF, true));
  return __int_as_float(__builtin_amdgcn_readlane(__float_as_int(x), 63));
}

// 16-lane (DPP row) allreduce via rotations 1,2,4,8: every lane gets its row's sum.
static __device__ __forceinline__ float sum16(float x) {
  x += __int_as_float(__builtin_amdgcn_update_dpp(0, __float_as_int(x), 0x121, 0xF, 0xF, true));
  x += __int_as_float(__builtin_amdgcn_update_dpp(0, __float_as_int(x), 0x122, 0xF, 0xF, true));
  x += __int_as_float(__builtin_amdgcn_update_dpp(0, __float_as_int(x), 0x124, 0xF, 0xF, true));
  x += __int_as_float(__builtin_amdgcn_update_dpp(0, __float_as_int(x), 0x128, 0xF, 0xF, true));
  return x;
}

// 16-channel dot with initial value: edge attrs as 8 packed f16 pairs vs
// pre-packed We pairs; s starts at init (folds xf+xr into the MAC chain).
static __device__ __forceinline__ float dot16h_i(const uint4* __restrict__ E,
                                                 const h2* __restrict__ Wch,
                                                 float s) {
#if __has_builtin(__builtin_amdgcn_fdot2)
  const h2* e = (const h2*)E;
#pragma unroll
  for (int j = 0; j < 8; ++j) s = __builtin_amdgcn_fdot2(e[j], Wch[j], s, false);
  return s;
#else
  const unsigned* u = (const unsigned*)E;
#pragma unroll
  for (int j = 0; j < 8; ++j) {
    union { unsigned v; h2 h; } cv; cv.v = u[j];
    s = fmaf((float)cv.h[0], (float)Wch[j][0], s);
    s = fmaf((float)cv.h[1], (float)Wch[j][1], s);
  }
  return s;
#endif
}

// ---------------- K1a: LDS-local histogram (NO global atomics) ----------------
// 48 blocks = 3 layers x 16 chunks of 20000 edges. Counters (80KB) live in LDS;
// replica written out coalesced. Kills the cross-XCD atomic line ping-pong that
// made the global-atomic hist 73.8us (WRITE 30MB on 240KB of counters).
struct LHArgs { const int* ei[3]; int* counts; };

__global__ __launch_bounds__(256) void lhist_kernel(LHArgs a) {
  __shared__ int lh[NV + 1];
  const int t = threadIdx.x;
  const int l = blockIdx.x >> 4, r = blockIdx.x & 15;
  for (int i = t; i < NV + 1; i += 256) lh[i] = 0;
  __syncthreads();
  const int4* d4 = (const int4*)(a.ei[l] + NE);
  const int q0 = r * (NE / NREP / 4), q1 = q0 + NE / NREP / 4;
  for (int q = q0 + t; q < q1; q += 256) {
    int4 d = d4[q];
    atomicAdd(&lh[d.x], 1);
    atomicAdd(&lh[d.y], 1);
    atomicAdd(&lh[d.z], 1);
    atomicAdd(&lh[d.w], 1);
  }
  __syncthreads();
  int* out = a.counts + (size_t)(l * NREP + r) * (NV + 1);
  for (int i = t; i < NV + 1; i += 256) out[i] = lh[i];
}

// ---------------- K1b: ea column sums (small LDS, full occupancy) -------------
// Also pre-warms ea into L3 for mega's scatter (R8 finding).
struct ColArgs { const float* ea[3]; float* easum[3]; };

__global__ __launch_bounds__(256) void colsum_kernel(ColArgs a) {
  const int t = threadIdx.x, cb = (int)blockIdx.x;   // 0..767
  const int l = cb >> 8, blk = cb & 255;
  const float4* ea4 = (const float4*)a.ea[l];
  const int cg = t & 3;
  int r = blk * 64 + (t >> 2);
  const int rstride = 256 * 64;
  float4 s = make_float4(0.f, 0.f, 0.f, 0.f);
  for (; r < NE; r += rstride) {
    float4 v = ea4[(size_t)r * 4 + cg];
    s.x += v.x; s.y += v.y; s.z += v.z; s.w += v.w;
  }
  __shared__ float4 red4[256];
  red4[t] = s;
  __syncthreads();
  if (t < 4) {
    float4 tot = make_float4(0.f, 0.f, 0.f, 0.f);
    for (int j = t; j < 256; j += 4) {
      float4 v = red4[j];
      tot.x += v.x; tot.y += v.y; tot.z += v.z; tot.w += v.w;
    }
    atomicAdd(&a.easum[l][t * 4 + 0], tot.x);
    atomicAdd(&a.easum[l][t * 4 + 1], tot.y);
    atomicAdd(&a.easum[l][t * 4 + 2], tot.z);
    atomicAdd(&a.easum[l][t * 4 + 3], tot.w);
  }
}

// ---------------- K2: scan (sums NREP replicas) + casts + proj + tables -------
struct CJob { const float* src; ushort* dst; int K, M; };
struct K2Args {
  const int* counts; int* offs; int* cursor;
  CJob jobs[9];
  unsigned* csr[3]; ushort* eab[3];
  const float *x, *Wp, *bp, *gp, *bep;
  ushort* h0;
  const float* easum;            // 3 x 16 (stride 16)
  const float* We[3];
  unsigned* wchx[3];             // [8][HC] h2 per layer
  float* esfO[3];                // [HC] per layer
};

__global__ __launch_bounds__(1024) void scan_proj_kernel(K2Args a) {
  const int b = blockIdx.x, t = threadIdx.x;
  if (b < 3) {
    const int* counts = a.counts + (size_t)b * NREP * (NV + 1);
    int* offs = a.offs + b * (NV + 1);
    int* cursor = a.cursor + b * NV;
    __shared__ int ws[16];
    __shared__ int wexcl[17];
    const int lane = t & 63, wid = t >> 6;
    const int base = t * 20;
    int v[20];
    int tot = 0;
#pragma unroll
    for (int j = 0; j < 20; ++j) {
      int i = base + j;
      int c = 0;
      if (i < NV) {
#pragma unroll
        for (int rr = 0; rr < NREP; ++rr) c += counts[(size_t)rr * (NV + 1) + i];
      }
      v[j] = c;
      tot += c;
    }
    int x = tot;
#pragma unroll
    for (int o = 1; o < 64; o <<= 1) {
      int yy = __shfl_up(x, o, 64);
      if (lane >= o) x += yy;
    }
    if (lane == 63) ws[wid] = x;
    __syncthreads();
    if (t == 0) {
      int r = 0;
#pragma unroll
      for (int j = 0; j < 16; ++j) { wexcl[j] = r; r += ws[j]; }
      wexcl[16] = r;
    }
    __syncthreads();
    int run = wexcl[wid] + (x - tot);
#pragma unroll
    for (int j = 0; j < 20; ++j) {
      int i = base + j;
      if (i < NV) { offs[i] = run; cursor[i] = run; }
      run += v[j];
    }
    if (t == 0) offs[NV] = wexcl[16];
  } else if (b < 19) {
    if (b == 3 && t < 3 * CSR_PAD) {
      int l = t >> 4, p = t & 15;
      a.csr[l][NE + p] = 0u;
      uint4 z = make_uint4(0, 0, 0, 0);
      *(uint4*)(a.eab[l] + (size_t)(NE + p) * 16) = z;
      *(uint4*)(a.eab[l] + (size_t)(NE + p) * 16 + 8) = z;
    }
#pragma unroll
    for (int j = 0; j < 9; ++j) {
      CJob jb = a.jobs[j];
      const int total = jb.M * jb.K;
      for (int i = (b - 3) * 1024 + t; i < total; i += 16 * 1024) {
        int m = i / jb.K, k = i - m * jb.K;
        jb.dst[i] = f2b(jb.src[(size_t)k * jb.M + m]);
      }
    }
  } else if (b < 19 + NV / 16) {
    // proj: 1250 blocks * 16 waves = 20000 rows, single sweep
    const int wid = t >> 6, lane = t & 63;
    const int row = (b - 19) * 16 + wid;
    float xv = a.x[(size_t)row * 64 + lane];
    float acc = a.bp[lane];
#pragma unroll
    for (int k = 0; k < 64; ++k) {
      float v = __shfl(xv, k, 64);
      acc = fmaf(v, a.Wp[k * 64 + lane], acc);
    }
    float s1 = wave_sum64(acc), s2 = wave_sum64(acc * acc);
    float mean = s1 * (1.0f / 64.0f);
    float var  = s2 * (1.0f / 64.0f) - mean * mean;
    float yv = (acc - mean) * rsqrtf(var + 1e-5f) * a.gp[lane] + a.bep[lane];
    float gel = 0.5f * yv * (1.0f + erff(yv * 0.70710678118654752f));
    a.h0[(size_t)row * 64 + lane] = f2b(gel);
  } else {
    // Wchx pack: layer0/1: 8*256 entries, layer2: 8*64; index e = k8*HC + c
    for (int i = t; i < 4608; i += 1024) {
      int l, e;
      if (i < 2048)      { l = 0; e = i; }
      else if (i < 4096) { l = 1; e = i - 2048; }
      else               { l = 2; e = i - 4096; }
      const int hcl = (l == 2) ? 64 : 256;
      int k8 = e / hcl, c = e - k8 * hcl;
      const float* We = a.We[l];
      a.wchx[l][e] = (unsigned)f2h(We[(2 * k8) * hcl + c]) |
                     ((unsigned)f2h(We[(2 * k8 + 1) * hcl + c]) << 16);
    }
    // esf[c] = (sum_k easum[k] * We[k][c]) / NE  (same fma order as before)
    for (int i = t; i < 576; i += 1024) {
      int l, c;
      if (i < 256)      { l = 0; c = i; }
      else if (i < 512) { l = 1; c = i - 256; }
      else              { l = 2; c = i - 512; }
      const int hcl = (l == 2) ? 64 : 256;
      const float* We = a.We[l];
      const float* es = a.easum + l * 16;
      float s = 0.f;
#pragma unroll
      for (int k8 = 0; k8 < 8; ++k8) {
        s = fmaf(es[2 * k8], We[(2 * k8) * hcl + c], s);
        s = fmaf(es[2 * k8 + 1], We[(2 * k8 + 1) * hcl + c], s);
      }
      a.esfO[l][c] = s * (1.0f / (float)NE);
    }
  }
}

// ---------------- K3: layer-0 GEMM + cursor-atomic scatter --------------------
struct K3Args {
  const ushort *A, *WT;
  const float *b0, *b1, *b2;
  ushort *O0, *O1; float* O2;
  int K, M1, M2, Mtot, NT;
  const int* ei[3]; const float* ea[3];
  int* cursor;
  unsigned* csr[3]; ushort* eab[3]; int HC[3];
};

__global__ __launch_bounds__(256) void mega_kernel(K3Args a) {
  __shared__ ushort As[128][40];
  __shared__ ushort Bs[64][40];
  const int t = threadIdx.x;
  const int b = (int)blockIdx.x;
  if (b < a.NT) {
    const int wave = t >> 6, lane = t & 63;
    const int mcols = a.Mtot >> 6;
    const int col0 = (b % mcols) * 64, row0 = (b / mcols) * 128;
    const int m_ = lane & 15, q = lane >> 4;
    f32x4 acc[2][4];
#pragma unroll
    for (int i = 0; i < 2; ++i)
#pragma unroll
      for (int j = 0; j < 4; ++j) acc[i][j] = (f32x4){0.f, 0.f, 0.f, 0.f};
    const int ar = t >> 1, ac = (t & 1) * 16;
    const int br = t >> 2, bcol = (t & 3) * 8;
    const ushort* Ap = a.A + (size_t)(row0 + ar) * a.K + ac;
    const ushort* Bp = a.WT + (size_t)(col0 + br) * a.K + bcol;
    const bool a_ok = (row0 + ar) < NV;
    for (int k0 = 0; k0 < a.K; k0 += 32) {
      uint4 av0 = make_uint4(0, 0, 0, 0), av1 = make_uint4(0, 0, 0, 0);
      if (a_ok) { av0 = *(const uint4*)(Ap + k0); av1 = *(const uint4*)(Ap + k0 + 8); }
      uint4 bv = *(const uint4*)(Bp + k0);
      *(uint4*)&As[ar][ac] = av0;
      *(uint4*)&As[ar][ac + 8] = av1;
      *(uint4*)&Bs[br][bcol] = bv;
      __syncthreads();
      bf16x8 a0 = *(const bf16x8*)&As[wave * 32 + m_][q * 8];
      bf16x8 a1 = *(const bf16x8*)&As[wave * 32 + 16 + m_][q * 8];
#pragma unroll
      for (int cf = 0; cf < 4; ++cf) {
        bf16x8 bfr = *(const bf16x8*)&Bs[cf * 16 + m_][q * 8];
        acc[0][cf] = __builtin_amdgcn_mfma_f32_16x16x32_bf16(a0, bfr, acc[0][cf], 0, 0, 0);
        acc[1][cf] = __builtin_amdgcn_mfma_f32_16x16x32_bf16(a1, bfr, acc[1][cf], 0, 0, 0);
      }
      __syncthreads();
    }
    const float* bias; int base, mode, Wd;
    if (col0 < a.M1)      { bias = a.b0; base = 0;    mode = 0; Wd = a.M1; }
    else if (col0 < a.M2) { bias = a.b1; base = a.M1; mode = 1; Wd = a.M2 - a.M1; }
    else                  { bias = a.b2; base = a.M2; mode = 2; Wd = a.Mtot - a.M2; }
#pragma unroll
    for (int rf = 0; rf < 2; ++rf) {
#pragma unroll
      for (int cf = 0; cf < 4; ++cf) {
        int col = col0 + cf * 16 + m_ - base;
        float bb = bias[col];
#pragma unroll
        for (int r = 0; r < 4; ++r) {
          int row = row0 + wave * 32 + rf * 16 + q * 4 + r;
          if (row < NV) {
            float v = acc[rf][cf][r] + bb;
            if (mode == 0)      a.O0[(size_t)row * Wd + col] = f2b(v);
            else if (mode == 1) a.O1[(size_t)row * Wd + col] = f2b(v);
            else                a.O2[(size_t)row * Wd + col] = v;
          }
        }
      }
    }
  } else {
    int gi = (b - a.NT) * 256 + t;            // 3750*256 = 3*NE exactly
    int l = gi / NE, i = gi - l * NE;
    int dst = a.ei[l][NE + i], src = a.ei[l][i];
    int pos = atomicAdd(&a.cursor[(size_t)l * NV + dst], 1);
    a.csr[l][pos] = (unsigned)(src * a.HC[l]);
    const float4* er = (const float4*)(a.ea[l] + (size_t)i * 16);
    float4 q0 = er[0], q1 = er[1], q2 = er[2], q3 = er[3];
    uint4 w0, w1;
    w0.x = (unsigned)f2h(q0.x) | ((unsigned)f2h(q0.y) << 16);
    w0.y = (unsigned)f2h(q0.z) | ((unsigned)f2h(q0.w) << 16);
    w0.z = (unsigned)f2h(q1.x) | ((unsigned)f2h(q1.y) << 16);
    w0.w = (unsigned)f2h(q1.z) | ((unsigned)f2h(q1.w) << 16);
    w1.x = (unsigned)f2h(q2.x) | ((unsigned)f2h(q2.y) << 16);
    w1.y = (unsigned)f2h(q2.z) | ((unsigned)f2h(q2.w) << 16);
    w1.z = (unsigned)f2h(q3.x) | ((unsigned)f2h(q3.y) << 16);
    w1.w = (unsigned)f2h(q3.z) | ((unsigned)f2h(q3.w) << 16);
    *(uint4*)(a.eab[l] + (size_t)pos * 16) = w0;
    *(uint4*)(a.eab[l] + (size_t)pos * 16 + 8) = w1;
  }
}

// ---------------- standalone GEMM for layers 1,2 ----------------
__global__ __launch_bounds__(256) void gemm_fused(
    const ushort* __restrict__ A, const ushort* __restrict__ WT,
    const float* __restrict__ b0, const float* __restrict__ b1,
    const float* __restrict__ b2,
    ushort* __restrict__ O0, ushort* __restrict__ O1, float* __restrict__ O2,
    int N, int K, int M1, int M2, int Mtot)
{
  __shared__ ushort As[128][40];
  __shared__ ushort Bs[64][40];
  const int t = threadIdx.x, wave = t >> 6, lane = t & 63;
  const int row0 = blockIdx.y * 128, col0 = blockIdx.x * 64;
  const int m_ = lane & 15, q = lane >> 4;
  f32x4 acc[2][4];
#pragma unroll
  for (int i = 0; i < 2; ++i)
#pragma unroll
    for (int j = 0; j < 4; ++j) acc[i][j] = (f32x4){0.f, 0.f, 0.f, 0.f};
  const int ar = t >> 1, ac = (t & 1) * 16;
  const int br = t >> 2, bcol = (t & 3) * 8;
  const ushort* Ap = A + (size_t)(row0 + ar) * K + ac;
  const ushort* Bp = WT + (size_t)(col0 + br) * K + bcol;
  const bool a_ok = (row0 + ar) < N;
  for (int k0 = 0; k0 < K; k0 += 32) {
    uint4 av0 = make_uint4(0, 0, 0, 0), av1 = make_uint4(0, 0, 0, 0);
    if (a_ok) { av0 = *(const uint4*)(Ap + k0); av1 = *(const uint4*)(Ap + k0 + 8); }
    uint4 bv = *(const uint4*)(Bp + k0);
    *(uint4*)&As[ar][ac] = av0;
    *(uint4*)&As[ar][ac + 8] = av1;
    *(uint4*)&Bs[br][bcol] = bv;
    __syncthreads();
    bf16x8 a0 = *(const bf16x8*)&As[wave * 32 + m_][q * 8];
    bf16x8 a1 = *(const bf16x8*)&As[wave * 32 + 16 + m_][q * 8];
#pragma unroll
    for (int cf = 0; cf < 4; ++cf) {
      bf16x8 bfr = *(const bf16x8*)&Bs[cf * 16 + m_][q * 8];
      acc[0][cf] = __builtin_amdgcn_mfma_f32_16x16x32_bf16(a0, bfr, acc[0][cf], 0, 0, 0);
      acc[1][cf] = __builtin_amdgcn_mfma_f32_16x16x32_bf16(a1, bfr, acc[1][cf], 0, 0, 0);
    }
    __syncthreads();
  }
  const float* bias; int base, mode, Wd;
  if (col0 < M1)      { bias = b0; base = 0;  mode = 0; Wd = M1; }
  else if (col0 < M2) { bias = b1; base = M1; mode = 1; Wd = M2 - M1; }
  else                { bias = b2; base = M2; mode = 2; Wd = Mtot - M2; }
#pragma unroll
  for (int rf = 0; rf < 2; ++rf) {
#pragma unroll
    for (int cf = 0; cf < 4; ++cf) {
      int col = col0 + cf * 16 + m_ - base;
      float bb = bias[col];
#pragma unroll
      for (int r = 0; r < 4; ++r) {
        int row = row0 + wave * 32 + rf * 16 + q * 4 + r;
        if (row < N) {
          float v = acc[rf][cf][r] + bb;
          if (mode == 0)      O0[(size_t)row * Wd + col] = f2b(v);
          else if (mode == 1) O1[(size_t)row * Wd + col] = f2b(v);
          else                O2[(size_t)row * Wd + col] = v;
        }
      }
    }
  }
}

// ---------------- H=4 agg: ONE WAVE PER NODE, 2-deep gather pipeline ----------
__global__ __launch_bounds__(256) void agg4_kernel(
    const ushort* __restrict__ eab, const unsigned* __restrict__ wchx,
    const float* __restrict__ esf,
    const ushort* __restrict__ xl, const ushort* __restrict__ xr,
    const float* __restrict__ att, const float* __restrict__ bc,
    const float* __restrict__ g, const float* __restrict__ be,
    const float* __restrict__ res,
    const int* __restrict__ offs, const unsigned* __restrict__ csr,
    ushort* __restrict__ houtb)
{
  const int t = threadIdx.x, lane = t & 63, wave = t >> 6;
  const int n = blockIdx.x * 4 + wave;          // NV divisible by 4
  const int cb = 4 * lane;
  const size_t rowb = (size_t)n * 256 + cb;
  const float L2E = 1.4426950408889634f;

  float4 atv = *(const float4*)(att + cb);
  float at[4] = {atv.x * L2E, atv.y * L2E, atv.z * L2E, atv.w * L2E};

  h2 Wch[4][8];
#pragma unroll
  for (int k8 = 0; k8 < 8; ++k8) {
    uint4 wv = *(const uint4*)(wchx + k8 * 256 + cb);
    Wch[0][k8] = u2h2(wv.x); Wch[1][k8] = u2h2(wv.y);
    Wch[2][k8] = u2h2(wv.z); Wch[3][k8] = u2h2(wv.w);
  }
  float4 esfv = *(const float4*)(esf + cb);
  const float* esfp = &esfv.x;

  uint2 qr = *(const uint2*)(xr + rowb);
  float xrv[4] = {blo(qr.x), bhi(qr.x), blo(qr.y), bhi(qr.y)};
  uint2 qn = *(const uint2*)(xl + rowb);
  float xln[4] = {blo(qn.x), bhi(qn.x), blo(qn.y), bhi(qn.y)};

  // self loop (analytic)
  float p = 0.f;
#pragma unroll
  for (int j = 0; j < 4; ++j) {
    float v = xln[j] + xrv[j] + esfp[j];
    v = v > 0.f ? v : 0.2f * v;
    p = fmaf(v, at[j], p);
  }
  float wself = exp2f(sum16(p));
  float acc[4];
#pragma unroll
  for (int j = 0; j < 4; ++j) acc[j] = wself * xln[j];
  float denom = wself;

  const int beg = __builtin_amdgcn_readfirstlane(offs[n]);
  const int end = __builtin_amdgcn_readfirstlane(offs[n + 1]);

  unsigned CA[2];                // csr for batch +4 (gather source this iter)
  uint4 EA[2][2];
  uint2 XL[2], XN1[2];
  {
    unsigned C0[2], C1[2];
#pragma unroll
    for (int k = 0; k < 2; ++k) C0[k] = csr[beg + k];
#pragma unroll
    for (int k = 0; k < 2; ++k) C1[k] = csr[beg + 2 + k];
#pragma unroll
    for (int k = 0; k < 2; ++k) CA[k] = csr[beg + 4 + k];
#pragma unroll
    for (int k = 0; k < 2; ++k) {
      const uint4* ep = (const uint4*)(eab + (size_t)(beg + k) * 16);
      EA[k][0] = ep[0]; EA[k][1] = ep[1];
    }
#pragma unroll
    for (int k = 0; k < 2; ++k)
      XL[k] = *(const uint2*)(xl + __builtin_amdgcn_readfirstlane(C0[k]) + cb);
#pragma unroll
    for (int k = 0; k < 2; ++k)
      XN1[k] = *(const uint2*)(xl + __builtin_amdgcn_readfirstlane(C1[k]) + cb);
  }

  for (int idx = beg; idx < end; idx += 2) {
    unsigned CB[2];
#pragma unroll
    for (int k = 0; k < 2; ++k) CB[k] = csr[idx + 6 + k];
    uint4 EB[2][2];
#pragma unroll
    for (int k = 0; k < 2; ++k) {
      const uint4* ep = (const uint4*)(eab + (size_t)(idx + 2 + k) * 16);
      EB[k][0] = ep[0]; EB[k][1] = ep[1];
    }
    uint2 XN2[2];
#pragma unroll
    for (int k = 0; k < 2; ++k)
      XN2[k] = *(const uint2*)(xl + __builtin_amdgcn_readfirstlane(CA[k]) + cb);

#pragma unroll
    for (int k = 0; k < 2; ++k) {
      float xf[4] = {blo(XL[k].x), bhi(XL[k].x), blo(XL[k].y), bhi(XL[k].y)};
      float pp = 0.f;
#pragma unroll
      for (int j = 0; j < 4; ++j) {
        float v = dot16h_i(EA[k], Wch[j], xf[j] + xrv[j]);
        v = v > 0.f ? v : 0.2f * v;             // leaky_relu(0.2)
        pp = fmaf(v, at[j], pp);
      }
      float S = sum16(pp);
      float w = (idx + k < end) ? exp2f(S) : 0.f;
#pragma unroll
      for (int j = 0; j < 4; ++j) acc[j] = fmaf(w, xf[j], acc[j]);
      denom += w;
    }
#pragma unroll
    for (int k = 0; k < 2; ++k) {
      EA[k][0] = EB[k][0]; EA[k][1] = EB[k][1];
      XL[k] = XN1[k]; XN1[k] = XN2[k]; CA[k] = CB[k];
    }
  }

  const float inv = 1.0f / (denom + 1e-16f);
  float4 bcv = *(const float4*)(bc + cb);
  float out[4];
  out[0] = acc[0] * inv + bcv.x; out[1] = acc[1] * inv + bcv.y;
  out[2] = acc[2] * inv + bcv.z; out[3] = acc[3] * inv + bcv.w;

  // LayerNorm over 256 channels
  float so1 = out[0] + out[1] + out[2] + out[3];
  float so2 = out[0] * out[0] + out[1] * out[1] + out[2] * out[2] + out[3] * out[3];
  float s1 = wave_sum64(so1), s2 = wave_sum64(so2);
  float mean = s1 * (1.0f / 256.0f);
  float var  = s2 * (1.0f / 256.0f) - mean * mean;
  float rstd = rsqrtf(var + 1e-5f);
  float4 gv = *(const float4*)(g + cb);
  float4 bev = *(const float4*)(be + cb);
  float4 rv = *(const float4*)(res + rowb);
  const float* gp = &gv.x; const float* bep = &bev.x; const float* rp = &rv.x;
  ushort ob[4];
#pragma unroll
  for (int j = 0; j < 4; ++j) {
    float y = (out[j] - mean) * rstd * gp[j] + bep[j];
    float gel = 0.5f * y * (1.0f + erff(y * 0.70710678118654752f));
    ob[j] = f2b(gel + rp[j]);
  }
  uint2 ov;
  ov.x = (unsigned)ob[0] | ((unsigned)ob[1] << 16);
  ov.y = (unsigned)ob[2] | ((unsigned)ob[3] << 16);
  *(uint2*)(houtb + rowb) = ov;
}

// ---------------- H=1 agg (layer 2): one wave per node, 2-deep pipeline -------
__global__ __launch_bounds__(256, 4) void agg1_kernel(
    const ushort* __restrict__ eab, const unsigned* __restrict__ wchx,
    const float* __restrict__ esf,
    const ushort* __restrict__ xl, const ushort* __restrict__ xr,
    const float* __restrict__ att, const float* __restrict__ bc,
    const float* __restrict__ g, const float* __restrict__ be,
    const float* __restrict__ res,
    const int* __restrict__ offs, const unsigned* __restrict__ csr,
    float* __restrict__ houtf)
{
  const int HC = 64;
  const int t = threadIdx.x, lane = t & 63, wave = t >> 6;
  const int n = blockIdx.x * 4 + wave;
  const int c = lane;

  const float xr_t = b2f(xr[(size_t)n * HC + c]);
  const float att_t = att[c] * 1.4426950408889634f;
  h2 Wch[8];
#pragma unroll
  for (int k8 = 0; k8 < 8; ++k8) Wch[k8] = u2h2(wchx[k8 * 64 + c]);
  const float eself = esf[c];
  const float xln = b2f(xl[(size_t)n * HC + c]);

  float vs = xln + xr_t + eself;
  vs = vs > 0.f ? vs : 0.2f * vs;
  const float wself = exp2f(wave_sum64(vs * att_t));
  float acc = wself * xln, denom = wself;

  const int beg = __builtin_amdgcn_readfirstlane(offs[n]);
  const int end = __builtin_amdgcn_readfirstlane(offs[n + 1]);

  unsigned CA[4];
  uint4 EA[4][2];
  float XL[4], XN1[4];
  {
    unsigned C0[4], C1[4];
#pragma unroll
    for (int k = 0; k < 4; ++k) C0[k] = csr[beg + k];
#pragma unroll
    for (int k = 0; k < 4; ++k) C1[k] = csr[beg + 4 + k];
#pragma unroll
    for (int k = 0; k < 4; ++k) CA[k] = csr[beg + 8 + k];
#pragma unroll
    for (int k = 0; k < 4; ++k) {
      const uint4* ep = (const uint4*)(eab + (size_t)(beg + k) * 16);
      EA[k][0] = ep[0]; EA[k][1] = ep[1];
    }
#pragma unroll
    for (int k = 0; k < 4; ++k)
      XL[k] = b2f(xl[__builtin_amdgcn_readfirstlane(C0[k]) + c]);
#pragma unroll
    for (int k = 0; k < 4; ++k)
      XN1[k] = b2f(xl[__builtin_amdgcn_readfirstlane(C1[k]) + c]);
  }

  for (int idx = beg; idx < end; idx += 4) {
    unsigned CB[4];
#pragma unroll
    for (int k = 0; k < 4; ++k) CB[k] = csr[idx + 12 + k];
    uint4 EB[4][2];
#pragma unroll
    for (int k = 0; k < 4; ++k) {
      const uint4* ep = (const uint4*)(eab + (size_t)(idx + 4 + k) * 16);
      EB[k][0] = ep[0]; EB[k][1] = ep[1];
    }
    float XN2[4];
#pragma unroll
    for (int k = 0; k < 4; ++k)
      XN2[k] = b2f(xl[__builtin_amdgcn_readfirstlane(CA[k]) + c]);

    float wv[4];
#pragma unroll
    for (int k = 0; k < 4; ++k) {
      float v = dot16h_i(EA[k], Wch, XL[k] + xr_t);
      v = v > 0.f ? v : 0.2f * v;
      float S = wave_sum64(v * att_t);
      wv[k] = (idx + k < end) ? exp2f(S) : 0.f;
    }
#pragma unroll
    for (int k = 0; k < 4; ++k) { acc = fmaf(wv[k], XL[k], acc); denom += wv[k]; }
#pragma unroll
    for (int k = 0; k < 4; ++k) {
      EA[k][0] = EB[k][0]; EA[k][1] = EB[k][1];
      XL[k] = XN1[k]; XN1[k] = XN2[k]; CA[k] = CB[k];
    }
  }

  float out = acc / (denom + 1e-16f) + bc[c];
  float s1 = wave_sum64(out), s2 = wave_sum64(out * out);
  float mean = s1 / (float)HC;
  float var  = s2 / (float)HC - mean * mean;
  float y = (out - mean) * rsqrtf(var + 1e-5f) * g[c] + be[c];
  float gel = 0.5f * y * (1.0f + erff(y * 0.70710678118654752f));
  houtf[(size_t)n * HC + c] = gel + res[(size_t)n * HC + c];
}

// ---------------- host launch ----------------
extern "C" void kernel_launch(void* const* d_in, const int* in_sizes, int n_in,
                              void* d_out, int out_size, void* d_ws, size_t ws_size,
                              hipStream_t stream)
{
  auto in = [&](int i) { return (const float*)d_in[i]; };
  // per-layer base 11 + 11*i: Wl, bl, Wr, br, We, att, bc, g, be, Wsk, bsk

  const int ic[3] = {64, 256, 256}, hc[3] = {256, 256, 64}, oc[3] = {256, 256, 64};
  const int CSRN = NE + CSR_PAD;

  // ---- workspace layout ----
  char* w = (char*)d_ws;
  size_t off = 0;
  auto alloc = [&](size_t bytes) { void* p = w + off; off = (off + bytes + 511) & ~(size_t)511; return p; };
  ushort* B1   = (ushort*)alloc((size_t)NV * 256 * 2);  // xl (bf16)
  ushort* B2   = (ushort*)alloc((size_t)NV * 256 * 2);  // xr (bf16)
  float*  B3   = (float*)alloc((size_t)NV * 256 * 4);   // res (f32)
  ushort* h0bf = (ushort*)alloc((size_t)NV * 64 * 2);
  ushort* h1bf = (ushort*)alloc((size_t)NV * 256 * 2);
  ushort* h2bf = (ushort*)alloc((size_t)NV * 256 * 2);
  ushort* Wcat[3];
  for (int i = 0; i < 3; ++i)
    Wcat[i] = (ushort*)alloc((size_t)(2 * hc[i] + oc[i]) * ic[i] * 2);
  float*    easumA  = (float*)alloc(3 * 64);                        // rounds to 512
  int*      countsA = (int*)alloc((size_t)3 * NREP * (NV + 1) * 4); // replicas
  int*      offsA   = (int*)alloc((size_t)3 * (NV + 1) * 4);
  int*      cursorA = (int*)alloc((size_t)3 * NV * 4);
  unsigned* csrA    = (unsigned*)alloc((size_t)3 * CSRN * 4);
  ushort*   eabA    = (ushort*)alloc((size_t)3 * CSRN * 16 * 2);
  unsigned* wchxA   = (unsigned*)alloc((size_t)4608 * 4);           // packed We (h2)
  float*    esfA    = (float*)alloc((size_t)576 * 4);               // self-loop esf

  // ---- node 1: zero easums only (counts fully written by lhist) ----
  hipMemsetAsync(easumA, 0, 512, stream);

  // ---- node 2a: LDS-local histogram (atomic-free globally) ----
  LHArgs lh;
  for (int i = 0; i < 3; ++i) lh.ei[i] = (const int*)d_in[1 + 2 * i];
  lh.counts = countsA;
  lhist_kernel<<<3 * NREP, 256, 0, stream>>>(lh);

  // ---- node 2b: ea column sums (streams + L3-warms ea) ----
  ColArgs ca;
  for (int i = 0; i < 3; ++i) {
    ca.ea[i] = in(2 + 2 * i);
    ca.easum[i] = easumA + i * 16;
  }
  colsum_kernel<<<768, 256, 0, stream>>>(ca);

  // ---- node 3: scan (sums replicas) + casts + pads + proj + agg tables ----
  K2Args k2;
  k2.counts = countsA; k2.offs = offsA; k2.cursor = cursorA;
  for (int i = 0; i < 3; ++i) {
    k2.jobs[i * 3 + 0] = {in(11 + 11 * i), Wcat[i],                             ic[i], hc[i]};
    k2.jobs[i * 3 + 1] = {in(13 + 11 * i), Wcat[i] + (size_t)hc[i] * ic[i],     ic[i], hc[i]};
    k2.jobs[i * 3 + 2] = {in(20 + 11 * i), Wcat[i] + (size_t)2 * hc[i] * ic[i], ic[i], oc[i]};
    k2.csr[i] = csrA + (size_t)i * CSRN;
    k2.eab[i] = eabA + (size_t)i * CSRN * 16;
    k2.We[i] = in(15 + 11 * i);
  }
  k2.x = in(0); k2.Wp = in(7); k2.bp = in(8); k2.gp = in(9); k2.bep = in(10);
  k2.h0 = h0bf;
  k2.easum = easumA;
  k2.wchx[0] = wchxA; k2.wchx[1] = wchxA + 2048; k2.wchx[2] = wchxA + 4096;
  k2.esfO[0] = esfA; k2.esfO[1] = esfA + 256; k2.esfO[2] = esfA + 512;
  scan_proj_kernel<<<19 + NV / 16 + 1, 1024, 0, stream>>>(k2);

  // ---- node 4: layer-0 GEMM + scatter (independent; merged) ----
  K3Args ga;
  ga.A = h0bf; ga.WT = Wcat[0];
  ga.b0 = in(12); ga.b1 = in(14); ga.b2 = in(21);
  ga.O0 = B1; ga.O1 = B2; ga.O2 = B3;
  ga.K = 64; ga.M1 = 256; ga.M2 = 512; ga.Mtot = 768;
  ga.NT = (768 / 64) * ((NV + 127) / 128);  // 12 * 157 = 1884
  for (int i = 0; i < 3; ++i) {
    ga.ei[i] = (const int*)d_in[1 + 2 * i];
    ga.ea[i] = in(2 + 2 * i);
    ga.csr[i] = csrA + (size_t)i * CSRN;
    ga.eab[i] = eabA + (size_t)i * CSRN * 16;
    ga.HC[i] = hc[i];
  }
  ga.cursor = cursorA;
  mega_kernel<<<ga.NT + 3750, 256, 0, stream>>>(ga);

  // ---- node 5: agg layer 0 ----
  agg4_kernel<<<NV / 4, 256, 0, stream>>>(
      eabA + 0, wchxA, esfA, B1, B2, in(16), in(17), in(18), in(19),
      B3, offsA, csrA, h1bf);

  // ---- node 6: gemm layer 1 ----
  gemm_fused<<<dim3(768 / 64, (NV + 127) / 128), 256, 0, stream>>>(
      h1bf, Wcat[1], in(23), in(25), in(32), B1, B2, B3, NV, 256, 256, 512, 768);

  // ---- node 7: agg layer 1 ----
  agg4_kernel<<<NV / 4, 256, 0, stream>>>(
      eabA + (size_t)CSRN * 16, wchxA + 2048, esfA + 256, B1, B2, in(27), in(28),
      in(29), in(30), B3, offsA + (NV + 1), csrA + (size_t)CSRN, h2bf);

  // ---- node 8: gemm layer 2 ----
  gemm_fused<<<dim3(192 / 64, (NV + 127) / 128), 256, 0, stream>>>(
      h2bf, Wcat[2], in(34), in(36), in(43), B1, B2, B3, NV, 256, 64, 128, 192);

  // ---- node 9: agg layer 2 -> d_out ----
  agg1_kernel<<<NV / 4, 256, 0, stream>>>(
      eabA + (size_t)2 * CSRN * 16, wchxA + 4096, esfA + 512, B1, B2, in(38), in(39),
      in(40), in(41), B3, offsA + 2 * (NV + 1), csrA + (size_t)2 * CSRN,
      (float*)d_out);
}

// Round 11
// 499.501 us; speedup vs baseline: 1.1821x; 1.1821x over previous
//
#include <hip/hip_runtime.h>
#include <hip/hip_bf16.h>
#include <math.h>

#define NV 20000
#define NE 320000
#define CSR_PAD 16
#define NREP 16                  // hist replicas per layer (LDS-local chunks)

typedef __attribute__((ext_vector_type(8))) short bf16x8;
typedef __attribute__((ext_vector_type(4))) float f32x4;
typedef __attribute__((ext_vector_type(2))) _Float16 h2;

static __device__ __forceinline__ ushort f2b(float f) {
  __hip_bfloat16 h = __float2bfloat16(f);
  return *reinterpret_cast<ushort*>(&h);
}
static __device__ __forceinline__ float b2f(ushort u) {
  union { ushort s[2]; float f; } c;
  c.s[0] = 0; c.s[1] = u;
  return c.f;
}
static __device__ __forceinline__ ushort f2h(float f) {
  _Float16 h = (_Float16)f;
  return *reinterpret_cast<ushort*>(&h);
}
static __device__ __forceinline__ float blo(unsigned u) { return __uint_as_float(u << 16); }
static __device__ __forceinline__ float bhi(unsigned u) { return __uint_as_float(u & 0xffff0000u); }
static __device__ __forceinline__ h2 u2h2(unsigned u) {
  union { unsigned v; h2 h; } c; c.v = u; return c.h;
}

// DPP wave-64 sum: lane 63 holds total, broadcast via readlane.
static __device__ __forceinline__ float wave_sum64(float x) {
  x += __int_as_float(__builtin_amdgcn_update_dpp(0, __float_as_int(x), 0x111, 0xF, 0xF, true));
  x += __int_as_float(__builtin_amdgcn_update_dpp(0, __float_as_int(x), 0x112, 0xF, 0xF, true));
  x += __int_as_float(__builtin_amdgcn_update_dpp(0, __float_as_int(x), 0x114, 0xF, 0xF, true));
  x += __int_as_float(__builtin_amdgcn_update_dpp(0, __float_as_int(x), 0x118, 0xF, 0xF, true));
  x += __int_as_float(__builtin_amdgcn_update_dpp(0, __float_as_int(x), 0x142, 0xA, 0xF, true));
  x += __int_as_float(__builtin_amdgcn_update_dpp(0, __float_as_int(x), 0x143, 0xC, 0xF, true));
  return __int_as_float(__builtin_amdgcn_readlane(__float_as_int(x), 63));
}

// 16-lane (DPP row) allreduce via rotations 1,2,4,8: every lane gets its row's sum.
static __device__ __forceinline__ float sum16(float x) {
  x += __int_as_float(__builtin_amdgcn_update_dpp(0, __float_as_int(x), 0x121, 0xF, 0xF, true));
  x += __int_as_float(__builtin_amdgcn_update_dpp(0, __float_as_int(x), 0x122, 0xF, 0xF, true));
  x += __int_as_float(__builtin_amdgcn_update_dpp(0, __float_as_int(x), 0x124, 0xF, 0xF, true));
  x += __int_as_float(__builtin_amdgcn_update_dpp(0, __float_as_int(x), 0x128, 0xF, 0xF, true));
  return x;
}

// 16-channel dot with initial value: edge attrs as 8 packed f16 pairs vs
// pre-packed We pairs; s starts at init (folds xf+xr into the MAC chain).
static __device__ __forceinline__ float dot16h_i(const uint4* __restrict__ E,
                                                 const h2* __restrict__ Wch,
                                                 float s) {
#if __has_builtin(__builtin_amdgcn_fdot2)
  const h2* e = (const h2*)E;
#pragma unroll
  for (int j = 0; j < 8; ++j) s = __builtin_amdgcn_fdot2(e[j], Wch[j], s, false);
  return s;
#else
  const unsigned* u = (const unsigned*)E;
#pragma unroll
  for (int j = 0; j < 8; ++j) {
    union { unsigned v; h2 h; } cv; cv.v = u[j];
    s = fmaf((float)cv.h[0], (float)Wch[j][0], s);
    s = fmaf((float)cv.h[1], (float)Wch[j][1], s);
  }
  return s;
#endif
}

// ---------------- K1a: LDS-local histogram (NO global atomics) ----------------
struct LHArgs { const int* ei[3]; int* counts; };

__global__ __launch_bounds__(256) void lhist_kernel(LHArgs a) {
  __shared__ int lh[NV + 1];
  const int t = threadIdx.x;
  const int l = blockIdx.x >> 4, r = blockIdx.x & 15;
  for (int i = t; i < NV + 1; i += 256) lh[i] = 0;
  __syncthreads();
  const int4* d4 = (const int4*)(a.ei[l] + NE);
  const int q0 = r * (NE / NREP / 4), q1 = q0 + NE / NREP / 4;
  for (int q = q0 + t; q < q1; q += 256) {
    int4 d = d4[q];
    atomicAdd(&lh[d.x], 1);
    atomicAdd(&lh[d.y], 1);
    atomicAdd(&lh[d.z], 1);
    atomicAdd(&lh[d.w], 1);
  }
  __syncthreads();
  int* out = a.counts + (size_t)(l * NREP + r) * (NV + 1);
  for (int i = t; i < NV + 1; i += 256) out[i] = lh[i];
}

// ---------------- K1b: ea column sums + replica reduction ---------------------
// [0,768): colsum streaming (also L3-warms ea for mega's scatter, R8 finding).
// [768, 768+30): coalesced reduction of the 16 hist replicas -> countsR.
// Runs after lhist (stream order) so replicas are complete; reduction is
// massively parallel & coalesced -- fixes R10's 3-CU serial replica sum.
struct ColArgs {
  const float* ea[3]; float* easum[3];
  const int* counts; int* countsR;
};

__global__ __launch_bounds__(256) void colsum_kernel(ColArgs a) {
  const int t = threadIdx.x, cb = (int)blockIdx.x;
  if (cb < 768) {
    const int l = cb >> 8, blk = cb & 255;
    const float4* ea4 = (const float4*)a.ea[l];
    const int cg = t & 3;
    int r = blk * 64 + (t >> 2);
    const int rstride = 256 * 64;
    float4 s = make_float4(0.f, 0.f, 0.f, 0.f);
    for (; r < NE; r += rstride) {
      float4 v = ea4[(size_t)r * 4 + cg];
      s.x += v.x; s.y += v.y; s.z += v.z; s.w += v.w;
    }
    __shared__ float4 red4[256];
    red4[t] = s;
    __syncthreads();
    if (t < 4) {
      float4 tot = make_float4(0.f, 0.f, 0.f, 0.f);
      for (int j = t; j < 256; j += 4) {
        float4 v = red4[j];
        tot.x += v.x; tot.y += v.y; tot.z += v.z; tot.w += v.w;
      }
      atomicAdd(&a.easum[l][t * 4 + 0], tot.x);
      atomicAdd(&a.easum[l][t * 4 + 1], tot.y);
      atomicAdd(&a.easum[l][t * 4 + 2], tot.z);
      atomicAdd(&a.easum[l][t * 4 + 3], tot.w);
    }
  } else {
    const int rb = cb - 768;                 // 0..29
    const int l = rb / 10, chunk = rb % 10;  // 10 chunks of 2048 per layer
    const int* cin = a.counts + (size_t)l * NREP * (NV + 1);
    int* cout = a.countsR + (size_t)l * (NV + 1);
#pragma unroll
    for (int step = 0; step < 8; ++step) {
      int i = chunk * 2048 + step * 256 + t;
      if (i < NV + 1) {
        int s = 0;
#pragma unroll
        for (int rr = 0; rr < NREP; ++rr) s += cin[(size_t)rr * (NV + 1) + i];
        cout[i] = s;
      }
    }
  }
}

// ---------------- K2: scan (single reduced array) + casts + proj + tables -----
struct CJob { const float* src; ushort* dst; int K, M; };
struct K2Args {
  const int* counts; int* offs; int* cursor;
  CJob jobs[9];
  unsigned* csr[3]; ushort* eab[3];
  const float *x, *Wp, *bp, *gp, *bep;
  ushort* h0;
  const float* easum;            // 3 x 16 (stride 16)
  const float* We[3];
  unsigned* wchx[3];             // [8][HC] h2 per layer
  float* esfO[3];                // [HC] per layer
};

__global__ __launch_bounds__(1024) void scan_proj_kernel(K2Args a) {
  const int b = blockIdx.x, t = threadIdx.x;
  if (b < 3) {
    const int* counts = a.counts + b * (NV + 1);
    int* offs = a.offs + b * (NV + 1);
    int* cursor = a.cursor + b * NV;
    __shared__ int ws[16];
    __shared__ int wexcl[17];
    const int lane = t & 63, wid = t >> 6;
    const int base = t * 20;
    int v[20];
    int tot = 0;
#pragma unroll
    for (int j = 0; j < 20; ++j) {
      int i = base + j;
      v[j] = (i < NV) ? counts[i] : 0;
      tot += v[j];
    }
    int x = tot;
#pragma unroll
    for (int o = 1; o < 64; o <<= 1) {
      int yy = __shfl_up(x, o, 64);
      if (lane >= o) x += yy;
    }
    if (lane == 63) ws[wid] = x;
    __syncthreads();
    if (t == 0) {
      int r = 0;
#pragma unroll
      for (int j = 0; j < 16; ++j) { wexcl[j] = r; r += ws[j]; }
      wexcl[16] = r;
    }
    __syncthreads();
    int run = wexcl[wid] + (x - tot);
#pragma unroll
    for (int j = 0; j < 20; ++j) {
      int i = base + j;
      if (i < NV) { offs[i] = run; cursor[i] = run; }
      run += v[j];
    }
    if (t == 0) offs[NV] = wexcl[16];
  } else if (b < 19) {
    if (b == 3 && t < 3 * CSR_PAD) {
      int l = t >> 4, p = t & 15;
      a.csr[l][NE + p] = 0u;
      uint4 z = make_uint4(0, 0, 0, 0);
      *(uint4*)(a.eab[l] + (size_t)(NE + p) * 16) = z;
      *(uint4*)(a.eab[l] + (size_t)(NE + p) * 16 + 8) = z;
    }
#pragma unroll
    for (int j = 0; j < 9; ++j) {
      CJob jb = a.jobs[j];
      const int total = jb.M * jb.K;
      for (int i = (b - 3) * 1024 + t; i < total; i += 16 * 1024) {
        int m = i / jb.K, k = i - m * jb.K;
        jb.dst[i] = f2b(jb.src[(size_t)k * jb.M + m]);
      }
    }
  } else if (b < 19 + NV / 16) {
    // proj: 1250 blocks * 16 waves = 20000 rows, single sweep
    const int wid = t >> 6, lane = t & 63;
    const int row = (b - 19) * 16 + wid;
    float xv = a.x[(size_t)row * 64 + lane];
    float acc = a.bp[lane];
#pragma unroll
    for (int k = 0; k < 64; ++k) {
      float v = __shfl(xv, k, 64);
      acc = fmaf(v, a.Wp[k * 64 + lane], acc);
    }
    float s1 = wave_sum64(acc), s2 = wave_sum64(acc * acc);
    float mean = s1 * (1.0f / 64.0f);
    float var  = s2 * (1.0f / 64.0f) - mean * mean;
    float yv = (acc - mean) * rsqrtf(var + 1e-5f) * a.gp[lane] + a.bep[lane];
    float gel = 0.5f * yv * (1.0f + erff(yv * 0.70710678118654752f));
    a.h0[(size_t)row * 64 + lane] = f2b(gel);
  } else {
    // Wchx pack: layer0/1: 8*256 entries, layer2: 8*64; index e = k8*HC + c
    for (int i = t; i < 4608; i += 1024) {
      int l, e;
      if (i < 2048)      { l = 0; e = i; }
      else if (i < 4096) { l = 1; e = i - 2048; }
      else               { l = 2; e = i - 4096; }
      const int hcl = (l == 2) ? 64 : 256;
      int k8 = e / hcl, c = e - k8 * hcl;
      const float* We = a.We[l];
      a.wchx[l][e] = (unsigned)f2h(We[(2 * k8) * hcl + c]) |
                     ((unsigned)f2h(We[(2 * k8 + 1) * hcl + c]) << 16);
    }
    // esf[c] = (sum_k easum[k] * We[k][c]) / NE  (same fma order as before)
    for (int i = t; i < 576; i += 1024) {
      int l, c;
      if (i < 256)      { l = 0; c = i; }
      else if (i < 512) { l = 1; c = i - 256; }
      else              { l = 2; c = i - 512; }
      const int hcl = (l == 2) ? 64 : 256;
      const float* We = a.We[l];
      const float* es = a.easum + l * 16;
      float s = 0.f;
#pragma unroll
      for (int k8 = 0; k8 < 8; ++k8) {
        s = fmaf(es[2 * k8], We[(2 * k8) * hcl + c], s);
        s = fmaf(es[2 * k8 + 1], We[(2 * k8 + 1) * hcl + c], s);
      }
      a.esfO[l][c] = s * (1.0f / (float)NE);
    }
  }
}

// ---------------- K3: layer-0 GEMM + cursor-atomic scatter --------------------
struct K3Args {
  const ushort *A, *WT;
  const float *b0, *b1, *b2;
  ushort *O0, *O1; float* O2;
  int K, M1, M2, Mtot, NT;
  const int* ei[3]; const float* ea[3];
  int* cursor;
  unsigned* csr[3]; ushort* eab[3]; int HC[3];
};

__global__ __launch_bounds__(256) void mega_kernel(K3Args a) {
  __shared__ ushort As[128][40];
  __shared__ ushort Bs[64][40];
  const int t = threadIdx.x;
  const int b = (int)blockIdx.x;
  if (b < a.NT) {
    const int wave = t >> 6, lane = t & 63;
    const int mcols = a.Mtot >> 6;
    const int col0 = (b % mcols) * 64, row0 = (b / mcols) * 128;
    const int m_ = lane & 15, q = lane >> 4;
    f32x4 acc[2][4];
#pragma unroll
    for (int i = 0; i < 2; ++i)
#pragma unroll
      for (int j = 0; j < 4; ++j) acc[i][j] = (f32x4){0.f, 0.f, 0.f, 0.f};
    const int ar = t >> 1, ac = (t & 1) * 16;
    const int br = t >> 2, bcol = (t & 3) * 8;
    const ushort* Ap = a.A + (size_t)(row0 + ar) * a.K + ac;
    const ushort* Bp = a.WT + (size_t)(col0 + br) * a.K + bcol;
    const bool a_ok = (row0 + ar) < NV;
    for (int k0 = 0; k0 < a.K; k0 += 32) {
      uint4 av0 = make_uint4(0, 0, 0, 0), av1 = make_uint4(0, 0, 0, 0);
      if (a_ok) { av0 = *(const uint4*)(Ap + k0); av1 = *(const uint4*)(Ap + k0 + 8); }
      uint4 bv = *(const uint4*)(Bp + k0);
      *(uint4*)&As[ar][ac] = av0;
      *(uint4*)&As[ar][ac + 8] = av1;
      *(uint4*)&Bs[br][bcol] = bv;
      __syncthreads();
      bf16x8 a0 = *(const bf16x8*)&As[wave * 32 + m_][q * 8];
      bf16x8 a1 = *(const bf16x8*)&As[wave * 32 + 16 + m_][q * 8];
#pragma unroll
      for (int cf = 0; cf < 4; ++cf) {
        bf16x8 bfr = *(const bf16x8*)&Bs[cf * 16 + m_][q * 8];
        acc[0][cf] = __builtin_amdgcn_mfma_f32_16x16x32_bf16(a0, bfr, acc[0][cf], 0, 0, 0);
        acc[1][cf] = __builtin_amdgcn_mfma_f32_16x16x32_bf16(a1, bfr, acc[1][cf], 0, 0, 0);
      }
      __syncthreads();
    }
    const float* bias; int base, mode, Wd;
    if (col0 < a.M1)      { bias = a.b0; base = 0;    mode = 0; Wd = a.M1; }
    else if (col0 < a.M2) { bias = a.b1; base = a.M1; mode = 1; Wd = a.M2 - a.M1; }
    else                  { bias = a.b2; base = a.M2; mode = 2; Wd = a.Mtot - a.M2; }
#pragma unroll
    for (int rf = 0; rf < 2; ++rf) {
#pragma unroll
      for (int cf = 0; cf < 4; ++cf) {
        int col = col0 + cf * 16 + m_ - base;
        float bb = bias[col];
#pragma unroll
        for (int r = 0; r < 4; ++r) {
          int row = row0 + wave * 32 + rf * 16 + q * 4 + r;
          if (row < NV) {
            float v = acc[rf][cf][r] + bb;
            if (mode == 0)      a.O0[(size_t)row * Wd + col] = f2b(v);
            else if (mode == 1) a.O1[(size_t)row * Wd + col] = f2b(v);
            else                a.O2[(size_t)row * Wd + col] = v;
          }
        }
      }
    }
  } else {
    int gi = (b - a.NT) * 256 + t;            // 3750*256 = 3*NE exactly
    int l = gi / NE, i = gi - l * NE;
    int dst = a.ei[l][NE + i], src = a.ei[l][i];
    int pos = atomicAdd(&a.cursor[(size_t)l * NV + dst], 1);
    a.csr[l][pos] = (unsigned)(src * a.HC[l]);
    const float4* er = (const float4*)(a.ea[l] + (size_t)i * 16);
    float4 q0 = er[0], q1 = er[1], q2 = er[2], q3 = er[3];
    uint4 w0, w1;
    w0.x = (unsigned)f2h(q0.x) | ((unsigned)f2h(q0.y) << 16);
    w0.y = (unsigned)f2h(q0.z) | ((unsigned)f2h(q0.w) << 16);
    w0.z = (unsigned)f2h(q1.x) | ((unsigned)f2h(q1.y) << 16);
    w0.w = (unsigned)f2h(q1.z) | ((unsigned)f2h(q1.w) << 16);
    w1.x = (unsigned)f2h(q2.x) | ((unsigned)f2h(q2.y) << 16);
    w1.y = (unsigned)f2h(q2.z) | ((unsigned)f2h(q2.w) << 16);
    w1.z = (unsigned)f2h(q3.x) | ((unsigned)f2h(q3.y) << 16);
    w1.w = (unsigned)f2h(q3.z) | ((unsigned)f2h(q3.w) << 16);
    *(uint4*)(a.eab[l] + (size_t)pos * 16) = w0;
    *(uint4*)(a.eab[l] + (size_t)pos * 16 + 8) = w1;
  }
}

// ---------------- standalone GEMM for layers 1,2 ----------------
__global__ __launch_bounds__(256) void gemm_fused(
    const ushort* __restrict__ A, const ushort* __restrict__ WT,
    const float* __restrict__ b0, const float* __restrict__ b1,
    const float* __restrict__ b2,
    ushort* __restrict__ O0, ushort* __restrict__ O1, float* __restrict__ O2,
    int N, int K, int M1, int M2, int Mtot)
{
  __shared__ ushort As[128][40];
  __shared__ ushort Bs[64][40];
  const int t = threadIdx.x, wave = t >> 6, lane = t & 63;
  const int row0 = blockIdx.y * 128, col0 = blockIdx.x * 64;
  const int m_ = lane & 15, q = lane >> 4;
  f32x4 acc[2][4];
#pragma unroll
  for (int i = 0; i < 2; ++i)
#pragma unroll
    for (int j = 0; j < 4; ++j) acc[i][j] = (f32x4){0.f, 0.f, 0.f, 0.f};
  const int ar = t >> 1, ac = (t & 1) * 16;
  const int br = t >> 2, bcol = (t & 3) * 8;
  const ushort* Ap = A + (size_t)(row0 + ar) * K + ac;
  const ushort* Bp = WT + (size_t)(col0 + br) * K + bcol;
  const bool a_ok = (row0 + ar) < N;
  for (int k0 = 0; k0 < K; k0 += 32) {
    uint4 av0 = make_uint4(0, 0, 0, 0), av1 = make_uint4(0, 0, 0, 0);
    if (a_ok) { av0 = *(const uint4*)(Ap + k0); av1 = *(const uint4*)(Ap + k0 + 8); }
    uint4 bv = *(const uint4*)(Bp + k0);
    *(uint4*)&As[ar][ac] = av0;
    *(uint4*)&As[ar][ac + 8] = av1;
    *(uint4*)&Bs[br][bcol] = bv;
    __syncthreads();
    bf16x8 a0 = *(const bf16x8*)&As[wave * 32 + m_][q * 8];
    bf16x8 a1 = *(const bf16x8*)&As[wave * 32 + 16 + m_][q * 8];
#pragma unroll
    for (int cf = 0; cf < 4; ++cf) {
      bf16x8 bfr = *(const bf16x8*)&Bs[cf * 16 + m_][q * 8];
      acc[0][cf] = __builtin_amdgcn_mfma_f32_16x16x32_bf16(a0, bfr, acc[0][cf], 0, 0, 0);
      acc[1][cf] = __builtin_amdgcn_mfma_f32_16x16x32_bf16(a1, bfr, acc[1][cf], 0, 0, 0);
    }
    __syncthreads();
  }
  const float* bias; int base, mode, Wd;
  if (col0 < M1)      { bias = b0; base = 0;  mode = 0; Wd = M1; }
  else if (col0 < M2) { bias = b1; base = M1; mode = 1; Wd = M2 - M1; }
  else                { bias = b2; base = M2; mode = 2; Wd = Mtot - M2; }
#pragma unroll
  for (int rf = 0; rf < 2; ++rf) {
#pragma unroll
    for (int cf = 0; cf < 4; ++cf) {
      int col = col0 + cf * 16 + m_ - base;
      float bb = bias[col];
#pragma unroll
      for (int r = 0; r < 4; ++r) {
        int row = row0 + wave * 32 + rf * 16 + q * 4 + r;
        if (row < N) {
          float v = acc[rf][cf][r] + bb;
          if (mode == 0)      O0[(size_t)row * Wd + col] = f2b(v);
          else if (mode == 1) O1[(size_t)row * Wd + col] = f2b(v);
          else                O2[(size_t)row * Wd + col] = v;
        }
      }
    }
  }
}

// ---------------- H=4 agg: ONE WAVE PER NODE, 2-deep gather pipeline ----------
__global__ __launch_bounds__(256) void agg4_kernel(
    const ushort* __restrict__ eab, const unsigned* __restrict__ wchx,
    const float* __restrict__ esf,
    const ushort* __restrict__ xl, const ushort* __restrict__ xr,
    const float* __restrict__ att, const float* __restrict__ bc,
    const float* __restrict__ g, const float* __restrict__ be,
    const float* __restrict__ res,
    const int* __restrict__ offs, const unsigned* __restrict__ csr,
    ushort* __restrict__ houtb)
{
  const int t = threadIdx.x, lane = t & 63, wave = t >> 6;
  const int n = blockIdx.x * 4 + wave;          // NV divisible by 4
  const int cb = 4 * lane;
  const size_t rowb = (size_t)n * 256 + cb;
  const float L2E = 1.4426950408889634f;

  float4 atv = *(const float4*)(att + cb);
  float at[4] = {atv.x * L2E, atv.y * L2E, atv.z * L2E, atv.w * L2E};

  h2 Wch[4][8];
#pragma unroll
  for (int k8 = 0; k8 < 8; ++k8) {
    uint4 wv = *(const uint4*)(wchx + k8 * 256 + cb);
    Wch[0][k8] = u2h2(wv.x); Wch[1][k8] = u2h2(wv.y);
    Wch[2][k8] = u2h2(wv.z); Wch[3][k8] = u2h2(wv.w);
  }
  float4 esfv = *(const float4*)(esf + cb);
  const float* esfp = &esfv.x;

  uint2 qr = *(const uint2*)(xr + rowb);
  float xrv[4] = {blo(qr.x), bhi(qr.x), blo(qr.y), bhi(qr.y)};
  uint2 qn = *(const uint2*)(xl + rowb);
  float xln[4] = {blo(qn.x), bhi(qn.x), blo(qn.y), bhi(qn.y)};

  // self loop (analytic)
  float p = 0.f;
#pragma unroll
  for (int j = 0; j < 4; ++j) {
    float v = xln[j] + xrv[j] + esfp[j];
    v = v > 0.f ? v : 0.2f * v;
    p = fmaf(v, at[j], p);
  }
  float wself = exp2f(sum16(p));
  float acc[4];
#pragma unroll
  for (int j = 0; j < 4; ++j) acc[j] = wself * xln[j];
  float denom = wself;

  const int beg = __builtin_amdgcn_readfirstlane(offs[n]);
  const int end = __builtin_amdgcn_readfirstlane(offs[n + 1]);

  unsigned CA[2];                // csr for batch +4 (gather source this iter)
  uint4 EA[2][2];
  uint2 XL[2], XN1[2];
  {
    unsigned C0[2], C1[2];
#pragma unroll
    for (int k = 0; k < 2; ++k) C0[k] = csr[beg + k];
#pragma unroll
    for (int k = 0; k < 2; ++k) C1[k] = csr[beg + 2 + k];
#pragma unroll
    for (int k = 0; k < 2; ++k) CA[k] = csr[beg + 4 + k];
#pragma unroll
    for (int k = 0; k < 2; ++k) {
      const uint4* ep = (const uint4*)(eab + (size_t)(beg + k) * 16);
      EA[k][0] = ep[0]; EA[k][1] = ep[1];
    }
#pragma unroll
    for (int k = 0; k < 2; ++k)
      XL[k] = *(const uint2*)(xl + __builtin_amdgcn_readfirstlane(C0[k]) + cb);
#pragma unroll
    for (int k = 0; k < 2; ++k)
      XN1[k] = *(const uint2*)(xl + __builtin_amdgcn_readfirstlane(C1[k]) + cb);
  }

  for (int idx = beg; idx < end; idx += 2) {
    unsigned CB[2];
#pragma unroll
    for (int k = 0; k < 2; ++k) CB[k] = csr[idx + 6 + k];
    uint4 EB[2][2];
#pragma unroll
    for (int k = 0; k < 2; ++k) {
      const uint4* ep = (const uint4*)(eab + (size_t)(idx + 2 + k) * 16);
      EB[k][0] = ep[0]; EB[k][1] = ep[1];
    }
    uint2 XN2[2];
#pragma unroll
    for (int k = 0; k < 2; ++k)
      XN2[k] = *(const uint2*)(xl + __builtin_amdgcn_readfirstlane(CA[k]) + cb);

#pragma unroll
    for (int k = 0; k < 2; ++k) {
      float xf[4] = {blo(XL[k].x), bhi(XL[k].x), blo(XL[k].y), bhi(XL[k].y)};
      float pp = 0.f;
#pragma unroll
      for (int j = 0; j < 4; ++j) {
        float v = dot16h_i(EA[k], Wch[j], xf[j] + xrv[j]);
        v = v > 0.f ? v : 0.2f * v;             // leaky_relu(0.2)
        pp = fmaf(v, at[j], pp);
      }
      float S = sum16(pp);
      float w = (idx + k < end) ? exp2f(S) : 0.f;
#pragma unroll
      for (int j = 0; j < 4; ++j) acc[j] = fmaf(w, xf[j], acc[j]);
      denom += w;
    }
#pragma unroll
    for (int k = 0; k < 2; ++k) {
      EA[k][0] = EB[k][0]; EA[k][1] = EB[k][1];
      XL[k] = XN1[k]; XN1[k] = XN2[k]; CA[k] = CB[k];
    }
  }

  const float inv = 1.0f / (denom + 1e-16f);
  float4 bcv = *(const float4*)(bc + cb);
  float out[4];
  out[0] = acc[0] * inv + bcv.x; out[1] = acc[1] * inv + bcv.y;
  out[2] = acc[2] * inv + bcv.z; out[3] = acc[3] * inv + bcv.w;

  // LayerNorm over 256 channels
  float so1 = out[0] + out[1] + out[2] + out[3];
  float so2 = out[0] * out[0] + out[1] * out[1] + out[2] * out[2] + out[3] * out[3];
  float s1 = wave_sum64(so1), s2 = wave_sum64(so2);
  float mean = s1 * (1.0f / 256.0f);
  float var  = s2 * (1.0f / 256.0f) - mean * mean;
  float rstd = rsqrtf(var + 1e-5f);
  float4 gv = *(const float4*)(g + cb);
  float4 bev = *(const float4*)(be + cb);
  float4 rv = *(const float4*)(res + rowb);
  const float* gp = &gv.x; const float* bep = &bev.x; const float* rp = &rv.x;
  ushort ob[4];
#pragma unroll
  for (int j = 0; j < 4; ++j) {
    float y = (out[j] - mean) * rstd * gp[j] + bep[j];
    float gel = 0.5f * y * (1.0f + erff(y * 0.70710678118654752f));
    ob[j] = f2b(gel + rp[j]);
  }
  uint2 ov;
  ov.x = (unsigned)ob[0] | ((unsigned)ob[1] << 16);
  ov.y = (unsigned)ob[2] | ((unsigned)ob[3] << 16);
  *(uint2*)(houtb + rowb) = ov;
}

// ---------------- H=1 agg (layer 2): one wave per node, 2-deep pipeline -------
__global__ __launch_bounds__(256, 4) void agg1_kernel(
    const ushort* __restrict__ eab, const unsigned* __restrict__ wchx,
    const float* __restrict__ esf,
    const ushort* __restrict__ xl, const ushort* __restrict__ xr,
    const float* __restrict__ att, const float* __restrict__ bc,
    const float* __restrict__ g, const float* __restrict__ be,
    const float* __restrict__ res,
    const int* __restrict__ offs, const unsigned* __restrict__ csr,
    float* __restrict__ houtf)
{
  const int HC = 64;
  const int t = threadIdx.x, lane = t & 63, wave = t >> 6;
  const int n = blockIdx.x * 4 + wave;
  const int c = lane;

  const float xr_t = b2f(xr[(size_t)n * HC + c]);
  const float att_t = att[c] * 1.4426950408889634f;
  h2 Wch[8];
#pragma unroll
  for (int k8 = 0; k8 < 8; ++k8) Wch[k8] = u2h2(wchx[k8 * 64 + c]);
  const float eself = esf[c];
  const float xln = b2f(xl[(size_t)n * HC + c]);

  float vs = xln + xr_t + eself;
  vs = vs > 0.f ? vs : 0.2f * vs;
  const float wself = exp2f(wave_sum64(vs * att_t));
  float acc = wself * xln, denom = wself;

  const int beg = __builtin_amdgcn_readfirstlane(offs[n]);
  const int end = __builtin_amdgcn_readfirstlane(offs[n + 1]);

  unsigned CA[4];
  uint4 EA[4][2];
  float XL[4], XN1[4];
  {
    unsigned C0[4], C1[4];
#pragma unroll
    for (int k = 0; k < 4; ++k) C0[k] = csr[beg + k];
#pragma unroll
    for (int k = 0; k < 4; ++k) C1[k] = csr[beg + 4 + k];
#pragma unroll
    for (int k = 0; k < 4; ++k) CA[k] = csr[beg + 8 + k];
#pragma unroll
    for (int k = 0; k < 4; ++k) {
      const uint4* ep = (const uint4*)(eab + (size_t)(beg + k) * 16);
      EA[k][0] = ep[0]; EA[k][1] = ep[1];
    }
#pragma unroll
    for (int k = 0; k < 4; ++k)
      XL[k] = b2f(xl[__builtin_amdgcn_readfirstlane(C0[k]) + c]);
#pragma unroll
    for (int k = 0; k < 4; ++k)
      XN1[k] = b2f(xl[__builtin_amdgcn_readfirstlane(C1[k]) + c]);
  }

  for (int idx = beg; idx < end; idx += 4) {
    unsigned CB[4];
#pragma unroll
    for (int k = 0; k < 4; ++k) CB[k] = csr[idx + 12 + k];
    uint4 EB[4][2];
#pragma unroll
    for (int k = 0; k < 4; ++k) {
      const uint4* ep = (const uint4*)(eab + (size_t)(idx + 4 + k) * 16);
      EB[k][0] = ep[0]; EB[k][1] = ep[1];
    }
    float XN2[4];
#pragma unroll
    for (int k = 0; k < 4; ++k)
      XN2[k] = b2f(xl[__builtin_amdgcn_readfirstlane(CA[k]) + c]);

    float wv[4];
#pragma unroll
    for (int k = 0; k < 4; ++k) {
      float v = dot16h_i(EA[k], Wch, XL[k] + xr_t);
      v = v > 0.f ? v : 0.2f * v;
      float S = wave_sum64(v * att_t);
      wv[k] = (idx + k < end) ? exp2f(S) : 0.f;
    }
#pragma unroll
    for (int k = 0; k < 4; ++k) { acc = fmaf(wv[k], XL[k], acc); denom += wv[k]; }
#pragma unroll
    for (int k = 0; k < 4; ++k) {
      EA[k][0] = EB[k][0]; EA[k][1] = EB[k][1];
      XL[k] = XN1[k]; XN1[k] = XN2[k]; CA[k] = CB[k];
    }
  }

  float out = acc / (denom + 1e-16f) + bc[c];
  float s1 = wave_sum64(out), s2 = wave_sum64(out * out);
  float mean = s1 / (float)HC;
  float var  = s2 / (float)HC - mean * mean;
  float y = (out - mean) * rsqrtf(var + 1e-5f) * g[c] + be[c];
  float gel = 0.5f * y * (1.0f + erff(y * 0.70710678118654752f));
  houtf[(size_t)n * HC + c] = gel + res[(size_t)n * HC + c];
}

// ---------------- host launch ----------------
extern "C" void kernel_launch(void* const* d_in, const int* in_sizes, int n_in,
                              void* d_out, int out_size, void* d_ws, size_t ws_size,
                              hipStream_t stream)
{
  auto in = [&](int i) { return (const float*)d_in[i]; };
  // per-layer base 11 + 11*i: Wl, bl, Wr, br, We, att, bc, g, be, Wsk, bsk

  const int ic[3] = {64, 256, 256}, hc[3] = {256, 256, 64}, oc[3] = {256, 256, 64};
  const int CSRN = NE + CSR_PAD;

  // ---- workspace layout ----
  char* w = (char*)d_ws;
  size_t off = 0;
  auto alloc = [&](size_t bytes) { void* p = w + off; off = (off + bytes + 511) & ~(size_t)511; return p; };
  ushort* B1   = (ushort*)alloc((size_t)NV * 256 * 2);  // xl (bf16)
  ushort* B2   = (ushort*)alloc((size_t)NV * 256 * 2);  // xr (bf16)
  float*  B3   = (float*)alloc((size_t)NV * 256 * 4);   // res (f32)
  ushort* h0bf = (ushort*)alloc((size_t)NV * 64 * 2);
  ushort* h1bf = (ushort*)alloc((size_t)NV * 256 * 2);
  ushort* h2bf = (ushort*)alloc((size_t)NV * 256 * 2);
  ushort* Wcat[3];
  for (int i = 0; i < 3; ++i)
    Wcat[i] = (ushort*)alloc((size_t)(2 * hc[i] + oc[i]) * ic[i] * 2);
  float*    easumA  = (float*)alloc(3 * 64);                        // rounds to 512
  int*      countsA = (int*)alloc((size_t)3 * NREP * (NV + 1) * 4); // replicas
  int*      countsR = (int*)alloc((size_t)3 * (NV + 1) * 4);       // reduced
  int*      offsA   = (int*)alloc((size_t)3 * (NV + 1) * 4);
  int*      cursorA = (int*)alloc((size_t)3 * NV * 4);
  unsigned* csrA    = (unsigned*)alloc((size_t)3 * CSRN * 4);
  ushort*   eabA    = (ushort*)alloc((size_t)3 * CSRN * 16 * 2);
  unsigned* wchxA   = (unsigned*)alloc((size_t)4608 * 4);           // packed We (h2)
  float*    esfA    = (float*)alloc((size_t)576 * 4);               // self-loop esf

  // ---- node 1: zero easums only (counts fully written by lhist) ----
  hipMemsetAsync(easumA, 0, 512, stream);

  // ---- node 2a: LDS-local histogram (atomic-free globally) ----
  LHArgs lh;
  for (int i = 0; i < 3; ++i) lh.ei[i] = (const int*)d_in[1 + 2 * i];
  lh.counts = countsA;
  lhist_kernel<<<3 * NREP, 256, 0, stream>>>(lh);

  // ---- node 2b: ea column sums + coalesced replica reduction ----
  ColArgs ca;
  for (int i = 0; i < 3; ++i) {
    ca.ea[i] = in(2 + 2 * i);
    ca.easum[i] = easumA + i * 16;
  }
  ca.counts = countsA;
  ca.countsR = countsR;
  colsum_kernel<<<768 + 30, 256, 0, stream>>>(ca);

  // ---- node 3: scan (reduced counts) + casts + pads + proj + agg tables ----
  K2Args k2;
  k2.counts = countsR; k2.offs = offsA; k2.cursor = cursorA;
  for (int i = 0; i < 3; ++i) {
    k2.jobs[i * 3 + 0] = {in(11 + 11 * i), Wcat[i],                             ic[i], hc[i]};
    k2.jobs[i * 3 + 1] = {in(13 + 11 * i), Wcat[i] + (size_t)hc[i] * ic[i],     ic[i], hc[i]};
    k2.jobs[i * 3 + 2] = {in(20 + 11 * i), Wcat[i] + (size_t)2 * hc[i] * ic[i], ic[i], oc[i]};
    k2.csr[i] = csrA + (size_t)i * CSRN;
    k2.eab[i] = eabA + (size_t)i * CSRN * 16;
    k2.We[i] = in(15 + 11 * i);
  }
  k2.x = in(0); k2.Wp = in(7); k2.bp = in(8); k2.gp = in(9); k2.bep = in(10);
  k2.h0 = h0bf;
  k2.easum = easumA;
  k2.wchx[0] = wchxA; k2.wchx[1] = wchxA + 2048; k2.wchx[2] = wchxA + 4096;
  k2.esfO[0] = esfA; k2.esfO[1] = esfA + 256; k2.esfO[2] = esfA + 512;
  scan_proj_kernel<<<19 + NV / 16 + 1, 1024, 0, stream>>>(k2);

  // ---- node 4: layer-0 GEMM + scatter (independent; merged) ----
  K3Args ga;
  ga.A = h0bf; ga.WT = Wcat[0];
  ga.b0 = in(12); ga.b1 = in(14); ga.b2 = in(21);
  ga.O0 = B1; ga.O1 = B2; ga.O2 = B3;
  ga.K = 64; ga.M1 = 256; ga.M2 = 512; ga.Mtot = 768;
  ga.NT = (768 / 64) * ((NV + 127) / 128);  // 12 * 157 = 1884
  for (int i = 0; i < 3; ++i) {
    ga.ei[i] = (const int*)d_in[1 + 2 * i];
    ga.ea[i] = in(2 + 2 * i);
    ga.csr[i] = csrA + (size_t)i * CSRN;
    ga.eab[i] = eabA + (size_t)i * CSRN * 16;
    ga.HC[i] = hc[i];
  }
  ga.cursor = cursorA;
  mega_kernel<<<ga.NT + 3750, 256, 0, stream>>>(ga);

  // ---- node 5: agg layer 0 ----
  agg4_kernel<<<NV / 4, 256, 0, stream>>>(
      eabA + 0, wchxA, esfA, B1, B2, in(16), in(17), in(18), in(19),
      B3, offsA, csrA, h1bf);

  // ---- node 6: gemm layer 1 ----
  gemm_fused<<<dim3(768 / 64, (NV + 127) / 128), 256, 0, stream>>>(
      h1bf, Wcat[1], in(23), in(25), in(32), B1, B2, B3, NV, 256, 256, 512, 768);

  // ---- node 7: agg layer 1 ----
  agg4_kernel<<<NV / 4, 256, 0, stream>>>(
      eabA + (size_t)CSRN * 16, wchxA + 2048, esfA + 256, B1, B2, in(27), in(28),
      in(29), in(30), B3, offsA + (NV + 1), csrA + (size_t)CSRN, h2bf);

  // ---- node 8: gemm layer 2 ----
  gemm_fused<<<dim3(192 / 64, (NV + 127) / 128), 256, 0, stream>>>(
      h2bf, Wcat[2], in(34), in(36), in(43), B1, B2, B3, NV, 256, 64, 128, 192);

  // ---- node 9: agg layer 2 -> d_out ----
  agg1_kernel<<<NV / 4, 256, 0, stream>>>(
      eabA + (size_t)2 * CSRN * 16, wchxA + 4096, esfA + 512, B1, B2, in(38), in(39),
      in(40), in(41), B3, offsA + 2 * (NV + 1), csrA + (size_t)2 * CSRN,
      (float*)d_out);
}